// Round 3
// baseline (674.579 us; speedup 1.0000x reference)
//
#include <hip/hip_runtime.h>
#include <stdint.h>

#define NPIX 6084      // 78*78 pixels / patches
#define NPAD 6144      // padded to 48*128
#define KDIM 2304      // 256*3*3
#define KB   (KDIM*2)  // row bytes in bf16 = 4608

typedef __attribute__((ext_vector_type(8))) short s16x8;
typedef __attribute__((ext_vector_type(4))) float f32x4;

__device__ __forceinline__ short f2bf(float f) {
  unsigned u = __builtin_bit_cast(unsigned, f);
  u += 0x7FFFu + ((u >> 16) & 1u);
  return (short)(u >> 16);
}
__device__ __forceinline__ float bf2f(short s) {
  unsigned u = ((unsigned)(unsigned short)s) << 16;
  return __builtin_bit_cast(float, u);
}

#define GL16(g, l)                                                            \
  __builtin_amdgcn_global_load_lds(                                           \
      (__attribute__((address_space(1))) unsigned int*)(g),                   \
      (__attribute__((address_space(3))) unsigned int*)(l), 16, 0, 0)

// ---------------- prep: cast patches f32 -> bf16, pad rows to 6144 ----------
__global__ __launch_bounds__(256) void k_prep_pat(const float* __restrict__ pat,
                                                  short* __restrict__ out) {
  int i = blockIdx.x * 256 + threadIdx.x;  // one 8-elem chunk
  int e0 = i * 8;
  int row = e0 / KDIM;
  s16x8 v;
  if (row < NPIX) {
    const float* s = pat + e0;
#pragma unroll
    for (int j = 0; j < 8; ++j) v[j] = f2bf(s[j]);
  } else {
#pragma unroll
    for (int j = 0; j < 8; ++j) v[j] = 0;
  }
  *(s16x8*)(out + e0) = v;
}

// ---------------- prep: im2col of x into bf16 [6144][2304] ------------------
__global__ __launch_bounds__(256) void k_prep_xcol(const float* __restrict__ x,
                                                   short* __restrict__ out) {
  int i = blockIdx.x * 256 + threadIdx.x;
  int e0 = i * 8;
  int m = e0 / KDIM;
  int k0 = e0 - m * KDIM;
  s16x8 v;
  if (m < NPIX) {
    int p = m / 78, q = m - p * 78;
#pragma unroll
    for (int j = 0; j < 8; ++j) {
      int k = k0 + j;
      int c = k / 9;
      int r = k - c * 9;
      int dy = r / 3, dx = r - dy * 3;
      v[j] = f2bf(x[c * 6400 + (p + dy) * 80 + (q + dx)]);
    }
  } else {
#pragma unroll
    for (int j = 0; j < 8; ++j) v[j] = 0;
  }
  *(s16x8*)(out + e0) = v;
}

// ---------------- GEMM: sim[pixel][patch] = A(xcol) . B(patches)^T ----------
// m97 structure: 128x128 tile, BK=32, 4 waves (2x2), 4x4 16x16x32 bf16 frags,
// global_load_lds width-16 staging, bf16 output.
__global__ __launch_bounds__(256) void k_gemm(const short* __restrict__ A,
                                              const short* __restrict__ B,
                                              short* __restrict__ C) {
  __shared__ short As[128 * 32];
  __shared__ short Bs[128 * 32];
  const int tid = threadIdx.x;
  const int w = tid >> 6, lane = tid & 63;
  const int wr = w >> 1, wc = w & 1;
  const int tm = blockIdx.y, tn = blockIdx.x;
  const char* Ab = (const char*)A + (size_t)tm * 128 * KB;
  const char* Bb = (const char*)B + (size_t)tn * 128 * KB;
  const int r0 = lane >> 2;          // row within 16-row chunk
  const int kbyte = (lane & 3) * 16; // byte offset within 64-byte k-row
  f32x4 acc[4][4] = {};

  const short* ap = &As[(wr * 64 + (lane & 15)) * 32 + (lane >> 4) * 8];
  const short* bp = &Bs[(wc * 64 + (lane & 15)) * 32 + (lane >> 4) * 8];

  for (int kk = 0; kk < KDIM; kk += 32) {
#pragma unroll
    for (int o = 0; o < 2; ++o) {
      int ch = o * 4 + w;            // 8 chunks of 1 KiB
      int r = ch * 16 + r0;
      GL16(Ab + (size_t)r * KB + kk * 2 + kbyte, &As[ch * 512]);
      GL16(Bb + (size_t)r * KB + kk * 2 + kbyte, &Bs[ch * 512]);
    }
    asm volatile("s_waitcnt vmcnt(0)" ::: "memory");
    __syncthreads();
    s16x8 a[4], b[4];
#pragma unroll
    for (int i = 0; i < 4; ++i) a[i] = *(const s16x8*)(ap + i * 512);
#pragma unroll
    for (int i = 0; i < 4; ++i) b[i] = *(const s16x8*)(bp + i * 512);
#pragma unroll
    for (int mi = 0; mi < 4; ++mi)
#pragma unroll
      for (int ni = 0; ni < 4; ++ni)
        acc[mi][ni] = __builtin_amdgcn_mfma_f32_16x16x32_bf16(
            a[mi], b[ni], acc[mi][ni], 0, 0, 0);
    __syncthreads();
  }

  const int rowb = tm * 128 + wr * 64 + (lane >> 4) * 4;
  const int colb = tn * 128 + wc * 64 + (lane & 15);
#pragma unroll
  for (int mi = 0; mi < 4; ++mi)
#pragma unroll
    for (int ni = 0; ni < 4; ++ni)
#pragma unroll
      for (int j = 0; j < 4; ++j)
        C[(size_t)(rowb + mi * 16 + j) * NPAD + colb + ni * 16] =
            f2bf(acc[mi][ni][j]);
}

// ------------- argmax per pixel row + f64 rescore of near-ties --------------
__global__ __launch_bounds__(256) void k_argmax(const short* __restrict__ sim,
                                                const float* __restrict__ x,
                                                const float* __restrict__ pat,
                                                int* __restrict__ amax) {
  __shared__ int cand[4][32];
  __shared__ int ccnt[4];
  const int tid = threadIdx.x, w = tid >> 6, lane = tid & 63;
  const int pix = blockIdx.x * 4 + w;  // grid is exactly 6084/4
  const short* row = sim + (size_t)pix * NPAD;

  float best = -1e30f;
  int bidx = 0;
  for (int it = 0; it < 12; ++it) {
    int k0 = (it * 64 + lane) * 8;
    if (k0 < NPIX) {
      s16x8 v = *(const s16x8*)(row + k0);
#pragma unroll
      for (int j = 0; j < 8; ++j) {
        int k = k0 + j;
        float f = bf2f(v[j]);
        if (k < NPIX && (f > best || (f == best && k < bidx))) {
          best = f; bidx = k;
        }
      }
    }
  }
  for (int off = 32; off; off >>= 1) {
    float ov = __shfl_down(best, off);
    int oi = __shfl_down(bidx, off);
    if (ov > best || (ov == best && oi < bidx)) { best = ov; bidx = oi; }
  }
  float maxv = __shfl(best, 0);

  if (lane == 0) ccnt[w] = 0;
  __syncthreads();

  const float thr = maxv - 4.0f;  // covers bf16 matmul + storage error
  for (int it = 0; it < 12; ++it) {
    int k0 = (it * 64 + lane) * 8;
    if (k0 < NPIX) {
      s16x8 v = *(const s16x8*)(row + k0);
#pragma unroll
      for (int j = 0; j < 8; ++j) {
        int k = k0 + j;
        float f = bf2f(v[j]);
        if (k < NPIX && f >= thr) {
          int pos = atomicAdd(&ccnt[w], 1);
          if (pos < 32) cand[w][pos] = k;
        }
      }
    }
  }
  __syncthreads();

  int n = ccnt[w] < 32 ? ccnt[w] : 32;
  const int p = pix / 78, q = pix - (pix / 78) * 78;
  double bests = -1e300;
  int bestk = 0;
  for (int ci = 0; ci < n; ++ci) {
    int k = cand[w][ci];
    double s = 0.0;
    for (int cc = lane; cc < 256; cc += 64) {
      const float* xb = x + cc * 6400 + p * 80 + q;
      const float* pb = pat + (size_t)k * KDIM + cc * 9;
#pragma unroll
      for (int dy = 0; dy < 3; ++dy)
#pragma unroll
        for (int dx = 0; dx < 3; ++dx)
          s += (double)xb[dy * 80 + dx] * (double)pb[dy * 3 + dx];
    }
    for (int off = 32; off; off >>= 1) s += __shfl_down(s, off);
    if (lane == 0 && (s > bests || (s == bests && k < bestk))) {
      bests = s; bestk = k;
    }
  }
  if (lane == 0) amax[pix] = bestk;
}

// ---------------- zero d_out (f32 accumulate target) ------------------------
// 1600 blocks * 256 threads * 16B = 6,553,600 B = exactly out_size (1.6384M f32)
__global__ __launch_bounds__(256) void k_zero(float4* __restrict__ out) {
  int i = blockIdx.x * 256 + threadIdx.x;
  out[i] = make_float4(0.f, 0.f, 0.f, 0.f);
}

// ------- scatter: block b = source pixel; add its winning patch into out ----
// Replaces the gather k_out: 57M random 4B loads -> 14M coalesced loads +
// 14M low-contention atomics (<=9 writers per output element).
__global__ __launch_bounds__(256) void k_scatter(const float* __restrict__ pat,
                                                 const int* __restrict__ amax,
                                                 float* __restrict__ out) {
  const int b = blockIdx.x;            // 6084 source pixels
  const int k = amax[b];
  const int p = b / 78, q = b - (b / 78) * 78;
  const float* src = pat + (size_t)k * KDIM;
#pragma unroll
  for (int j = 0; j < 9; ++j) {        // 2304 / 256 = 9 coalesced sweeps
    int e = j * 256 + threadIdx.x;
    float v = src[e];
    int c = e / 9;
    int r = e - c * 9;
    int dy = r / 3, dx = r - dy * 3;
    atomicAdd(&out[c * 6400 + (p + dy) * 80 + (q + dx)], v);
  }
}

// ---------------- divide in place by analytic overlap count -----------------
__global__ __launch_bounds__(256) void k_div(float* __restrict__ out) {
  int i = blockIdx.x * 256 + threadIdx.x;  // 6400*256 = 1,638,400 exact
  int xx = i % 80;
  int rest = i / 80;
  int yy = rest % 80;
  int p0 = yy - 2 > 0 ? yy - 2 : 0, p1 = yy < 77 ? yy : 77;
  int q0 = xx - 2 > 0 ? xx - 2 : 0, q1 = xx < 77 ? xx : 77;
  int cnt = (p1 - p0 + 1) * (q1 - q0 + 1);
  out[i] = out[i] / (float)cnt;
}

extern "C" void kernel_launch(void* const* d_in, const int* in_sizes, int n_in,
                              void* d_out, int out_size, void* d_ws,
                              size_t ws_size, hipStream_t stream) {
  const float* x = (const float*)d_in[0];    // (1,256,80,80) f32
  const float* pat = (const float*)d_in[1];  // (6084,256,3,3) f32
  float* out = (float*)d_out;                // (1,256,80,80) f32
  char* ws = (char*)d_ws;

  short* patB = (short*)ws;                          // 28,311,552 B
  short* xcol = (short*)(ws + 28311552);             // 28,311,552 B
  short* sim  = (short*)(ws + 2 * 28311552);         // 75,497,472 B
  int*   amax = (int*)(ws + 2 * 28311552 + 75497472);// 24,336 B

  k_prep_pat<<<6912, 256, 0, stream>>>(pat, patB);
  k_prep_xcol<<<6912, 256, 0, stream>>>(x, xcol);
  k_gemm<<<dim3(48, 48), 256, 0, stream>>>(xcol, patB, sim);
  k_argmax<<<1521, 256, 0, stream>>>(sim, x, pat, amax);
  k_zero<<<1600, 256, 0, stream>>>((float4*)out);
  k_scatter<<<6084, 256, 0, stream>>>(pat, amax, out);
  k_div<<<6400, 256, 0, stream>>>(out);
}

// Round 5
// 459.371 us; speedup vs baseline: 1.4685x; 1.4685x over previous
//
#include <hip/hip_runtime.h>
#include <stdint.h>

#define NPIX 6084      // 78*78 pixels / patches
#define NPAD 6144      // padded to 48*128
#define KDIM 2304      // 256*3*3
#define KB   (KDIM*2)  // row bytes in bf16 = 4608

typedef __attribute__((ext_vector_type(8))) short s16x8;
typedef __attribute__((ext_vector_type(4))) float f32x4;

__device__ __forceinline__ short f2bf(float f) {
  unsigned u = __builtin_bit_cast(unsigned, f);
  u += 0x7FFFu + ((u >> 16) & 1u);
  return (short)(u >> 16);
}
__device__ __forceinline__ float bf2f(short s) {
  unsigned u = ((unsigned)(unsigned short)s) << 16;
  return __builtin_bit_cast(float, u);
}

#define GL16(g, l)                                                            \
  __builtin_amdgcn_global_load_lds(                                           \
      (__attribute__((address_space(1))) unsigned int*)(g),                   \
      (__attribute__((address_space(3))) unsigned int*)(l), 16, 0, 0)

// ---------------- prep: cast patches f32 -> bf16, pad rows to 6144 ----------
__global__ __launch_bounds__(256) void k_prep_pat(const float* __restrict__ pat,
                                                  short* __restrict__ out) {
  int i = blockIdx.x * 256 + threadIdx.x;  // one 8-elem chunk
  int e0 = i * 8;
  int row = e0 / KDIM;
  s16x8 v;
  if (row < NPIX) {
    const float* s = pat + e0;
#pragma unroll
    for (int j = 0; j < 8; ++j) v[j] = f2bf(s[j]);
  } else {
#pragma unroll
    for (int j = 0; j < 8; ++j) v[j] = 0;
  }
  *(s16x8*)(out + e0) = v;
}

// ---------------- prep: im2col of x into bf16 [6144][2304] ------------------
__global__ __launch_bounds__(256) void k_prep_xcol(const float* __restrict__ x,
                                                   short* __restrict__ out) {
  int i = blockIdx.x * 256 + threadIdx.x;
  int e0 = i * 8;
  int m = e0 / KDIM;
  int k0 = e0 - m * KDIM;
  s16x8 v;
  if (m < NPIX) {
    int p = m / 78, q = m - p * 78;
#pragma unroll
    for (int j = 0; j < 8; ++j) {
      int k = k0 + j;
      int c = k / 9;
      int r = k - c * 9;
      int dy = r / 3, dx = r - dy * 3;
      v[j] = f2bf(x[c * 6400 + (p + dy) * 80 + (q + dx)]);
    }
  } else {
#pragma unroll
    for (int j = 0; j < 8; ++j) v[j] = 0;
  }
  *(s16x8*)(out + e0) = v;
}

// ---------------- GEMM: sim[pixel][patch] = A(xcol) . B(patches)^T ----------
// m97 structure: 128x128 tile, BK=32, 4 waves (2x2), 4x4 16x16x32 bf16 frags,
// global_load_lds width-16 staging, bf16 output.
__global__ __launch_bounds__(256) void k_gemm(const short* __restrict__ A,
                                              const short* __restrict__ B,
                                              short* __restrict__ C) {
  __shared__ short As[128 * 32];
  __shared__ short Bs[128 * 32];
  const int tid = threadIdx.x;
  const int w = tid >> 6, lane = tid & 63;
  const int wr = w >> 1, wc = w & 1;
  const int tm = blockIdx.y, tn = blockIdx.x;
  const char* Ab = (const char*)A + (size_t)tm * 128 * KB;
  const char* Bb = (const char*)B + (size_t)tn * 128 * KB;
  const int r0 = lane >> 2;          // row within 16-row chunk
  const int kbyte = (lane & 3) * 16; // byte offset within 64-byte k-row
  f32x4 acc[4][4] = {};

  const short* ap = &As[(wr * 64 + (lane & 15)) * 32 + (lane >> 4) * 8];
  const short* bp = &Bs[(wc * 64 + (lane & 15)) * 32 + (lane >> 4) * 8];

  for (int kk = 0; kk < KDIM; kk += 32) {
#pragma unroll
    for (int o = 0; o < 2; ++o) {
      int ch = o * 4 + w;            // 8 chunks of 1 KiB
      int r = ch * 16 + r0;
      GL16(Ab + (size_t)r * KB + kk * 2 + kbyte, &As[ch * 512]);
      GL16(Bb + (size_t)r * KB + kk * 2 + kbyte, &Bs[ch * 512]);
    }
    asm volatile("s_waitcnt vmcnt(0)" ::: "memory");
    __syncthreads();
    s16x8 a[4], b[4];
#pragma unroll
    for (int i = 0; i < 4; ++i) a[i] = *(const s16x8*)(ap + i * 512);
#pragma unroll
    for (int i = 0; i < 4; ++i) b[i] = *(const s16x8*)(bp + i * 512);
#pragma unroll
    for (int mi = 0; mi < 4; ++mi)
#pragma unroll
      for (int ni = 0; ni < 4; ++ni)
        acc[mi][ni] = __builtin_amdgcn_mfma_f32_16x16x32_bf16(
            a[mi], b[ni], acc[mi][ni], 0, 0, 0);
    __syncthreads();
  }

  const int rowb = tm * 128 + wr * 64 + (lane >> 4) * 4;
  const int colb = tn * 128 + wc * 64 + (lane & 15);
#pragma unroll
  for (int mi = 0; mi < 4; ++mi)
#pragma unroll
    for (int ni = 0; ni < 4; ++ni)
#pragma unroll
      for (int j = 0; j < 4; ++j)
        C[(size_t)(rowb + mi * 16 + j) * NPAD + colb + ni * 16] =
            f2bf(acc[mi][ni][j]);
}

// ------------- argmax per pixel row + f64 rescore of near-ties --------------
__global__ __launch_bounds__(256) void k_argmax(const short* __restrict__ sim,
                                                const float* __restrict__ x,
                                                const float* __restrict__ pat,
                                                int* __restrict__ amax) {
  __shared__ int cand[4][32];
  __shared__ int ccnt[4];
  const int tid = threadIdx.x, w = tid >> 6, lane = tid & 63;
  const int pix = blockIdx.x * 4 + w;  // grid is exactly 6084/4
  const short* row = sim + (size_t)pix * NPAD;

  float best = -1e30f;
  int bidx = 0;
  for (int it = 0; it < 12; ++it) {
    int k0 = (it * 64 + lane) * 8;
    if (k0 < NPIX) {
      s16x8 v = *(const s16x8*)(row + k0);
#pragma unroll
      for (int j = 0; j < 8; ++j) {
        int k = k0 + j;
        float f = bf2f(v[j]);
        if (k < NPIX && (f > best || (f == best && k < bidx))) {
          best = f; bidx = k;
        }
      }
    }
  }
  for (int off = 32; off; off >>= 1) {
    float ov = __shfl_down(best, off);
    int oi = __shfl_down(bidx, off);
    if (ov > best || (ov == best && oi < bidx)) { best = ov; bidx = oi; }
  }
  float maxv = __shfl(best, 0);

  if (lane == 0) ccnt[w] = 0;
  __syncthreads();

  const float thr = maxv - 4.0f;  // covers bf16 matmul + storage error
  for (int it = 0; it < 12; ++it) {
    int k0 = (it * 64 + lane) * 8;
    if (k0 < NPIX) {
      s16x8 v = *(const s16x8*)(row + k0);
#pragma unroll
      for (int j = 0; j < 8; ++j) {
        int k = k0 + j;
        float f = bf2f(v[j]);
        if (k < NPIX && f >= thr) {
          int pos = atomicAdd(&ccnt[w], 1);
          if (pos < 32) cand[w][pos] = k;
        }
      }
    }
  }
  __syncthreads();

  int n = ccnt[w] < 32 ? ccnt[w] : 32;
  const int p = pix / 78, q = pix - (pix / 78) * 78;
  double bests = -1e300;
  int bestk = 0;
  for (int ci = 0; ci < n; ++ci) {
    int k = cand[w][ci];
    double s = 0.0;
    for (int cc = lane; cc < 256; cc += 64) {
      const float* xb = x + cc * 6400 + p * 80 + q;
      const float* pb = pat + (size_t)k * KDIM + cc * 9;
#pragma unroll
      for (int dy = 0; dy < 3; ++dy)
#pragma unroll
        for (int dx = 0; dx < 3; ++dx)
          s += (double)xb[dy * 80 + dx] * (double)pb[dy * 3 + dx];
    }
    for (int off = 32; off; off >>= 1) s += __shfl_down(s, off);
    if (lane == 0 && (s > bests || (s == bests && k < bestk))) {
      bests = s; bestk = k;
    }
  }
  if (lane == 0) amax[pix] = bestk;
}

// ------- scatter9: collision-free scatter into 9 shift planes ---------------
// plane[r][pos][c], r=3*dy+dx, pos=(p+dy)*80+(q+dx), c contiguous -> all
// reads AND writes fully coalesced, no atomics (fixed r => shift => unique).
__global__ __launch_bounds__(256) void k_scat9(const float* __restrict__ pat,
                                               const int* __restrict__ amax,
                                               float* __restrict__ plane) {
  __shared__ float lp[KDIM];
  const int b = blockIdx.x;            // 6084 source pixels
  const int k = amax[b];
  const int p = b / 78, q = b - (b / 78) * 78;
  const float* src = pat + (size_t)k * KDIM;
#pragma unroll
  for (int j = 0; j < 9; ++j) lp[j * 256 + threadIdx.x] = src[j * 256 + threadIdx.x];
  __syncthreads();
  const int c = threadIdx.x;
#pragma unroll
  for (int r = 0; r < 9; ++r) {
    int dy = r / 3, dx = r - dy * 3;
    int pos = (p + dy) * 80 + (q + dx);   // always in [0,6400)
    plane[(size_t)r * 1638400 + pos * 256 + c] = lp[c * 9 + r];
  }
}

// ------- reduce: out[c][pix] = sum over valid planes / analytic count -------
// 400 blocks x 16 pixels; threads = c (256). Reads coalesced 1KB per (pix,r).
__global__ __launch_bounds__(256) void k_reduce(const float* __restrict__ plane,
                                                float* __restrict__ out) {
  const int c = threadIdx.x;
  const int pix0 = blockIdx.x * 16;
  for (int i = 0; i < 16; ++i) {
    int pix = pix0 + i;
    int yy = pix / 80, xx = pix - (pix / 80) * 80;
    float s = 0.f;
    int cnt = 0;
#pragma unroll
    for (int r = 0; r < 9; ++r) {
      int dy = r / 3, dx = r - dy * 3;
      int p = yy - dy, q = xx - dx;
      if (p >= 0 && p < 78 && q >= 0 && q < 78) {
        s += plane[(size_t)r * 1638400 + pix * 256 + c];
        ++cnt;
      }
    }
    out[c * 6400 + pix] = s / (float)cnt;
  }
}

extern "C" void kernel_launch(void* const* d_in, const int* in_sizes, int n_in,
                              void* d_out, int out_size, void* d_ws,
                              size_t ws_size, hipStream_t stream) {
  const float* x = (const float*)d_in[0];    // (1,256,80,80) f32
  const float* pat = (const float*)d_in[1];  // (6084,256,3,3) f32
  float* out = (float*)d_out;                // (1,256,80,80) f32
  char* ws = (char*)d_ws;

  short* patB = (short*)ws;                          // 28,311,552 B
  short* xcol = (short*)(ws + 28311552);             // 28,311,552 B
  short* sim  = (short*)(ws + 2 * 28311552);         // 75,497,472 B
  float* plane = (float*)sim;                        // 58,982,400 B (overlays dead sim)
  int*   amax = (int*)(ws + 2 * 28311552 + 75497472);// 24,336 B

  k_prep_pat<<<6912, 256, 0, stream>>>(pat, patB);
  k_prep_xcol<<<6912, 256, 0, stream>>>(x, xcol);
  k_gemm<<<dim3(48, 48), 256, 0, stream>>>(xcol, patB, sim);
  k_argmax<<<1521, 256, 0, stream>>>(sim, x, pat, amax);
  k_scat9<<<6084, 256, 0, stream>>>(pat, amax, plane);
  k_reduce<<<400, 256, 0, stream>>>(plane, out);
}

// Round 7
// 456.483 us; speedup vs baseline: 1.4778x; 1.0063x over previous
//
#include <hip/hip_runtime.h>
#include <stdint.h>

#define NPIX 6084      // 78*78 pixels / patches
#define NPAD 6144      // padded to 48*128 (= 24*256)
#define KDIM 2304      // 256*3*3
#define KB   (KDIM*2)  // row bytes in bf16 = 4608
#define NT   36        // K-tiles of 64

typedef __attribute__((ext_vector_type(8))) short s16x8;
typedef __attribute__((ext_vector_type(4))) float f32x4;

__device__ __forceinline__ short f2bf(float f) {
  unsigned u = __builtin_bit_cast(unsigned, f);
  u += 0x7FFFu + ((u >> 16) & 1u);
  return (short)(u >> 16);
}
__device__ __forceinline__ float bf2f(short s) {
  unsigned u = ((unsigned)(unsigned short)s) << 16;
  return __builtin_bit_cast(float, u);
}

#define GL16(g, l)                                                            \
  __builtin_amdgcn_global_load_lds(                                           \
      (__attribute__((address_space(1))) unsigned int*)(g),                   \
      (__attribute__((address_space(3))) unsigned int*)(l), 16, 0, 0)

// ---------------- prep: cast patches f32 -> bf16, pad rows to 6144 ----------
__global__ __launch_bounds__(256) void k_prep_pat(const float* __restrict__ pat,
                                                  short* __restrict__ out) {
  int i = blockIdx.x * 256 + threadIdx.x;  // one 8-elem chunk
  int e0 = i * 8;
  int row = e0 / KDIM;
  s16x8 v;
  if (row < NPIX) {
    const float* s = pat + e0;
#pragma unroll
    for (int j = 0; j < 8; ++j) v[j] = f2bf(s[j]);
  } else {
#pragma unroll
    for (int j = 0; j < 8; ++j) v[j] = 0;
  }
  *(s16x8*)(out + e0) = v;
}

// ---------------- prep: im2col of x into bf16 [6144][2304] ------------------
__global__ __launch_bounds__(256) void k_prep_xcol(const float* __restrict__ x,
                                                   short* __restrict__ out) {
  int i = blockIdx.x * 256 + threadIdx.x;
  int e0 = i * 8;
  int m = e0 / KDIM;
  int k0 = e0 - m * KDIM;
  s16x8 v;
  if (m < NPIX) {
    int p = m / 78, q = m - p * 78;
#pragma unroll
    for (int j = 0; j < 8; ++j) {
      int k = k0 + j;
      int c = k / 9;
      int r = k - c * 9;
      int dy = r / 3, dx = r - dy * 3;
      v[j] = f2bf(x[c * 6400 + (p + dy) * 80 + (q + dx)]);
    }
  } else {
#pragma unroll
    for (int j = 0; j < 8; ++j) v[j] = 0;
  }
  *(s16x8*)(out + e0) = v;
}

// ---------------- GEMM: 256x256 tile, BK=64, 8-phase counted-vmcnt ----------
// T3+T4 (8-phase, vmcnt(6) at P4/P8 only) + T2 (st_16x32 swizzle via
// pre-swizzled global source + swizzled ds_read) + T5 (setprio around MFMA).
// RACE FIX vs round 6: every barrier is an asm("s_barrier":::"memory") so the
// compiler cannot move GL16/ds_read across it (raw builtin s_barrier is NOT a
// memory fence); BARL fuses barrier+lgkmcnt(0) in one asm; GL16 LDS dest is
// the wave-uniform base (HW adds lane*16).
__global__ __launch_bounds__(512, 2) void k_gemm(const short* __restrict__ A,
                                                 const short* __restrict__ B,
                                                 short* __restrict__ C) {
  __shared__ __align__(1024) char smem[131072];  // [par][A 32K | B 32K]
  const int tid = threadIdx.x;
  const int w = tid >> 6, lane = tid & 63;
  const int wr = w >> 2, wc = w & 3;  // 2M x 4N
  const int tm = blockIdx.y, tn = blockIdx.x;
  const char* Ab = (const char*)A + (size_t)tm * 256 * KB;
  const char* Bb = (const char*)B + (size_t)tn * 256 * KB;

  // staging per-lane constants (pre-swizzled source: lds bit9 = lane>=32)
  const int srccol = ((lane & 7) * 16) ^ (lane & 32);
  const int lrow = lane >> 3;
  // ds_read per-lane constants (swizzle bit = row bit2 = lane bit2)
  const int fragRow = lane & 15;
  const int fragCol = ((lane >> 4) * 16) ^ (((lane >> 2) & 1) << 5);
  const int aOff = (wr * 128 + fragRow) * 128 + fragCol;
  const int bOff = 32768 + (wc * 64 + fragRow) * 128 + fragCol;

  f32x4 acc[8][4] = {};
  s16x8 a[4][2];     // current A mh: 4 mi x 2 ks
  s16x8 b[2][2][2];  // both B halves: [nh][ni2][ks]

#define STAGE_A(par, hs, kt)                                                  \
  _Pragma("unroll") for (int j = 0; j < 2; ++j) {                             \
    int c = w * 2 + j;                                                        \
    int rb = (c < 8) ? (hs)*64 + c * 8 : 128 + (hs)*64 + (c - 8) * 8;         \
    GL16(Ab + (size_t)(rb + lrow) * KB + (kt)*128 + srccol,                   \
         smem + (par)*65536 + rb * 128);                                      \
  }
#define STAGE_B(par, hs, kt)                                                  \
  _Pragma("unroll") for (int j = 0; j < 2; ++j) {                             \
    int c = w * 2 + j;                                                        \
    int rb = (c >> 2) * 64 + (hs)*32 + (c & 3) * 8;                           \
    GL16(Bb + (size_t)(rb + lrow) * KB + (kt)*128 + srccol,                   \
         smem + (par)*65536 + 32768 + rb * 128);                              \
  }
#define LDA(par, mh)                                                          \
  _Pragma("unroll") for (int mi2 = 0; mi2 < 4; ++mi2)                         \
  _Pragma("unroll") for (int ks = 0; ks < 2; ++ks)                            \
    a[mi2][ks] = *(const s16x8*)(smem + (par)*65536 + aOff + (mh)*8192 +      \
                                 mi2 * 2048 + ks * 64);
#define LDB(par, nh)                                                          \
  _Pragma("unroll") for (int ni2 = 0; ni2 < 2; ++ni2)                         \
  _Pragma("unroll") for (int ks = 0; ks < 2; ++ks)                            \
    b[nh][ni2][ks] = *(const s16x8*)(smem + (par)*65536 + bOff + (nh)*4096 +  \
                                     ni2 * 2048 + ks * 64);
#define VM6() asm volatile("s_waitcnt vmcnt(6)" ::: "memory")
#define BAR() asm volatile("s_barrier" ::: "memory")
#define BARL() asm volatile("s_barrier\n\ts_waitcnt lgkmcnt(0)" ::: "memory")
#define QM(mh, nh)                                                            \
  do {                                                                        \
    __builtin_amdgcn_s_setprio(1);                                            \
    _Pragma("unroll") for (int mi2 = 0; mi2 < 4; ++mi2)                       \
    _Pragma("unroll") for (int ni2 = 0; ni2 < 2; ++ni2)                       \
    _Pragma("unroll") for (int ks = 0; ks < 2; ++ks)                          \
      acc[(mh)*4 + mi2][(nh)*2 + ni2] =                                       \
          __builtin_amdgcn_mfma_f32_16x16x32_bf16(                            \
              a[mi2][ks], b[nh][ni2][ks], acc[(mh)*4 + mi2][(nh)*2 + ni2],    \
              0, 0, 0);                                                       \
    __builtin_amdgcn_s_setprio(0);                                            \
    BAR();                                                                    \
  } while (0)

  // prologue: t0 fully (par0), t1 first 3 halves (par1); vmcnt(6) -> t0 landed
  STAGE_A(0, 0, 0); STAGE_B(0, 0, 0); STAGE_B(0, 1, 0); STAGE_A(0, 1, 0);
  STAGE_A(1, 0, 1); STAGE_B(1, 0, 1); STAGE_B(1, 1, 1);
  VM6();
  BAR();

#pragma unroll 1
  for (int i = 0; i < NT / 2; ++i) {
    const int t2 = (2 * i + 2 < NT) ? 2 * i + 2 : NT - 1;  // clamped prefetch
    const int t3 = (2 * i + 3 < NT) ? 2 * i + 3 : NT - 1;
    // P1: consume e(mh0,nh0); stage odd tile's last half (Ao h1)
    LDA(0, 0); LDB(0, 0);
    STAGE_A(1, 1, 2 * i + 1);
    BARL(); QM(0, 0);
    // P2: consume e(mh0,nh1); stage Ae h0 of t+2 (freed P1)
    LDB(0, 1);
    STAGE_A(0, 0, t2);
    BARL(); QM(0, 1);
    // P3: consume e(mh1,nh1); stage Be h0 of t+2 (freed P1)
    LDA(0, 1);
    STAGE_B(0, 0, t2);
    BARL(); QM(1, 1);
    // P4: stage Be h1 of t+2 (freed P2); vmcnt(6) -> odd tile complete
    STAGE_B(0, 1, t2);
    VM6();
    BARL(); QM(1, 0);
    // P5: consume o(mh0,nh0); stage Ae h1 of t+2 (freed P3)
    LDA(1, 0); LDB(1, 0);
    STAGE_A(0, 1, t2);
    BARL(); QM(0, 0);
    // P6: stage Ao h0 of t+3 (freed P5)
    LDB(1, 1);
    STAGE_A(1, 0, t3);
    BARL(); QM(0, 1);
    // P7: stage Bo h0 of t+3 (freed P5)
    LDA(1, 1);
    STAGE_B(1, 0, t3);
    BARL(); QM(1, 1);
    // P8: stage Bo h1 of t+3 (freed P6); vmcnt(6) -> next even tile complete
    STAGE_B(1, 1, t3);
    VM6();
    BARL(); QM(1, 0);
  }

  // epilogue: write bf16 sim
  const int rowb = tm * 256 + wr * 128 + (lane >> 4) * 4;
  const int colb = tn * 256 + wc * 64 + (lane & 15);
#pragma unroll
  for (int mi = 0; mi < 8; ++mi)
#pragma unroll
    for (int ni = 0; ni < 4; ++ni)
#pragma unroll
      for (int j = 0; j < 4; ++j)
        C[(size_t)(rowb + mi * 16 + j) * NPAD + colb + ni * 16] =
            f2bf(acc[mi][ni][j]);
}

// ------------- argmax per pixel row + f64 rescore of near-ties --------------
__global__ __launch_bounds__(256) void k_argmax(const short* __restrict__ sim,
                                                const float* __restrict__ x,
                                                const float* __restrict__ pat,
                                                int* __restrict__ amax) {
  __shared__ int cand[4][32];
  __shared__ int ccnt[4];
  const int tid = threadIdx.x, w = tid >> 6, lane = tid & 63;
  const int pix = blockIdx.x * 4 + w;  // grid is exactly 6084/4
  const short* row = sim + (size_t)pix * NPAD;

  float best = -1e30f;
  int bidx = 0;
  for (int it = 0; it < 12; ++it) {
    int k0 = (it * 64 + lane) * 8;
    if (k0 < NPIX) {
      s16x8 v = *(const s16x8*)(row + k0);
#pragma unroll
      for (int j = 0; j < 8; ++j) {
        int k = k0 + j;
        float f = bf2f(v[j]);
        if (k < NPIX && (f > best || (f == best && k < bidx))) {
          best = f; bidx = k;
        }
      }
    }
  }
  for (int off = 32; off; off >>= 1) {
    float ov = __shfl_down(best, off);
    int oi = __shfl_down(bidx, off);
    if (ov > best || (ov == best && oi < bidx)) { best = ov; bidx = oi; }
  }
  float maxv = __shfl(best, 0);

  if (lane == 0) ccnt[w] = 0;
  __syncthreads();

  const float thr = maxv - 4.0f;  // covers bf16 matmul + storage error
  for (int it = 0; it < 12; ++it) {
    int k0 = (it * 64 + lane) * 8;
    if (k0 < NPIX) {
      s16x8 v = *(const s16x8*)(row + k0);
#pragma unroll
      for (int j = 0; j < 8; ++j) {
        int k = k0 + j;
        float f = bf2f(v[j]);
        if (k < NPIX && f >= thr) {
          int pos = atomicAdd(&ccnt[w], 1);
          if (pos < 32) cand[w][pos] = k;
        }
      }
    }
  }
  __syncthreads();

  int n = ccnt[w] < 32 ? ccnt[w] : 32;
  const int p = pix / 78, q = pix - (pix / 78) * 78;
  double bests = -1e300;
  int bestk = 0;
  for (int ci = 0; ci < n; ++ci) {
    int k = cand[w][ci];
    double s = 0.0;
    for (int cc = lane; cc < 256; cc += 64) {
      const float* xb = x + cc * 6400 + p * 80 + q;
      const float* pb = pat + (size_t)k * KDIM + cc * 9;
#pragma unroll
      for (int dy = 0; dy < 3; ++dy)
#pragma unroll
        for (int dx = 0; dx < 3; ++dx)
          s += (double)xb[dy * 80 + dx] * (double)pb[dy * 3 + dx];
    }
    for (int off = 32; off; off >>= 1) s += __shfl_down(s, off);
    if (lane == 0 && (s > bests || (s == bests && k < bestk))) {
      bests = s; bestk = k;
    }
  }
  if (lane == 0) amax[pix] = bestk;
}

// ------- scatter9: collision-free scatter into 9 shift planes ---------------
__global__ __launch_bounds__(256) void k_scat9(const float* __restrict__ pat,
                                               const int* __restrict__ amax,
                                               float* __restrict__ plane) {
  __shared__ float lp[KDIM];
  const int b = blockIdx.x;            // 6084 source pixels
  const int k = amax[b];
  const int p = b / 78, q = b - (b / 78) * 78;
  const float* src = pat + (size_t)k * KDIM;
#pragma unroll
  for (int j = 0; j < 9; ++j) lp[j * 256 + threadIdx.x] = src[j * 256 + threadIdx.x];
  __syncthreads();
  const int c = threadIdx.x;
#pragma unroll
  for (int r = 0; r < 9; ++r) {
    int dy = r / 3, dx = r - dy * 3;
    int pos = (p + dy) * 80 + (q + dx);   // always in [0,6400)
    plane[(size_t)r * 1638400 + pos * 256 + c] = lp[c * 9 + r];
  }
}

// ------- reduce: out[c][pix] = sum over valid planes / analytic count -------
__global__ __launch_bounds__(256) void k_reduce(const float* __restrict__ plane,
                                                float* __restrict__ out) {
  const int c = threadIdx.x;
  const int pix0 = blockIdx.x * 16;
  for (int i = 0; i < 16; ++i) {
    int pix = pix0 + i;
    int yy = pix / 80, xx = pix - (pix / 80) * 80;
    float s = 0.f;
    int cnt = 0;
#pragma unroll
    for (int r = 0; r < 9; ++r) {
      int dy = r / 3, dx = r - dy * 3;
      int p = yy - dy, q = xx - dx;
      if (p >= 0 && p < 78 && q >= 0 && q < 78) {
        s += plane[(size_t)r * 1638400 + pix * 256 + c];
        ++cnt;
      }
    }
    out[c * 6400 + pix] = s / (float)cnt;
  }
}

extern "C" void kernel_launch(void* const* d_in, const int* in_sizes, int n_in,
                              void* d_out, int out_size, void* d_ws,
                              size_t ws_size, hipStream_t stream) {
  const float* x = (const float*)d_in[0];    // (1,256,80,80) f32
  const float* pat = (const float*)d_in[1];  // (6084,256,3,3) f32
  float* out = (float*)d_out;                // (1,256,80,80) f32
  char* ws = (char*)d_ws;

  short* patB = (short*)ws;                          // 28,311,552 B
  short* xcol = (short*)(ws + 28311552);             // 28,311,552 B
  short* sim  = (short*)(ws + 2 * 28311552);         // 75,497,472 B
  float* plane = (float*)sim;                        // 58,982,400 B (overlays dead sim)
  int*   amax = (int*)(ws + 2 * 28311552 + 75497472);// 24,336 B

  k_prep_pat<<<6912, 256, 0, stream>>>(pat, patB);
  k_prep_xcol<<<6912, 256, 0, stream>>>(x, xcol);
  k_gemm<<<dim3(24, 24), 512, 0, stream>>>(xcol, patB, sim);
  k_argmax<<<1521, 256, 0, stream>>>(sim, x, pat, amax);
  k_scat9<<<6084, 256, 0, stream>>>(pat, amax, plane);
  k_reduce<<<400, 256, 0, stream>>>(plane, out);
}

// Round 8
// 437.254 us; speedup vs baseline: 1.5428x; 1.0440x over previous
//
#include <hip/hip_runtime.h>
#include <stdint.h>

#define NPIX 6084      // 78*78 pixels / patches
#define NPAD 6144      // padded to 48*128 (= 24*256)
#define KDIM 2304      // 256*3*3
#define KB   (KDIM*2)  // row bytes in bf16 = 4608
#define NT   36        // K-tiles of 64

typedef __attribute__((ext_vector_type(8))) short s16x8;
typedef __attribute__((ext_vector_type(4))) float f32x4;

__device__ __forceinline__ short f2bf(float f) {
  unsigned u = __builtin_bit_cast(unsigned, f);
  u += 0x7FFFu + ((u >> 16) & 1u);
  return (short)(u >> 16);
}
__device__ __forceinline__ float bf2f(short s) {
  unsigned u = ((unsigned)(unsigned short)s) << 16;
  return __builtin_bit_cast(float, u);
}

#define GL16(g, l)                                                            \
  __builtin_amdgcn_global_load_lds(                                           \
      (__attribute__((address_space(1))) unsigned int*)(g),                   \
      (__attribute__((address_space(3))) unsigned int*)(l), 16, 0, 0)

// ---------------- prep: cast patches f32 -> bf16, pad rows to 6144 ----------
__global__ __launch_bounds__(256) void k_prep_pat(const float* __restrict__ pat,
                                                  short* __restrict__ out) {
  int i = blockIdx.x * 256 + threadIdx.x;  // one 8-elem chunk
  int e0 = i * 8;
  int row = e0 / KDIM;
  s16x8 v;
  if (row < NPIX) {
    const float* s = pat + e0;
#pragma unroll
    for (int j = 0; j < 8; ++j) v[j] = f2bf(s[j]);
  } else {
#pragma unroll
    for (int j = 0; j < 8; ++j) v[j] = 0;
  }
  *(s16x8*)(out + e0) = v;
}

// ---------------- prep: im2col of x into bf16 [6144][2304] ------------------
__global__ __launch_bounds__(256) void k_prep_xcol(const float* __restrict__ x,
                                                   short* __restrict__ out) {
  int i = blockIdx.x * 256 + threadIdx.x;
  int e0 = i * 8;
  int m = e0 / KDIM;
  int k0 = e0 - m * KDIM;
  s16x8 v;
  if (m < NPIX) {
    int p = m / 78, q = m - p * 78;
#pragma unroll
    for (int j = 0; j < 8; ++j) {
      int k = k0 + j;
      int c = k / 9;
      int r = k - c * 9;
      int dy = r / 3, dx = r - dy * 3;
      v[j] = f2bf(x[c * 6400 + (p + dy) * 80 + (q + dx)]);
    }
  } else {
#pragma unroll
    for (int j = 0; j < 8; ++j) v[j] = 0;
  }
  *(s16x8*)(out + e0) = v;
}

// ---------------- GEMM: 256x256 tile, BK=64, 8-phase counted-vmcnt ----------
// T3+T4 (8-phase, vmcnt(6) at P4/P8 only) + T2 (3-bit XOR swizzle, G4 form:
// byte ^= (row&7)<<4, via pre-swizzled global source + swizzled ds_read) +
// T5 (setprio around MFMA). Barriers are asm s_barrier with "memory" clobber
// (compiler fence); GL16 dest is the wave-uniform base.
// SWIZZLE FIX vs round 7: 1-bit XOR left an 8-way conflict (1.6e7 counter);
// 3-bit (row&7)<<4 spreads each stripe's 8 rows over all 8 16B slots.
// XOR applied AFTER adding ks*64 (bit6 aliases between add and xor).
__global__ __launch_bounds__(512, 2) void k_gemm(const short* __restrict__ A,
                                                 const short* __restrict__ B,
                                                 short* __restrict__ C) {
  __shared__ __align__(1024) char smem[131072];  // [par][A 32K | B 32K]
  const int tid = threadIdx.x;
  const int w = tid >> 6, lane = tid & 63;
  const int wr = w >> 2, wc = w & 3;  // 2M x 4N
  const int tm = blockIdx.y, tn = blockIdx.x;
  const char* Ab = (const char*)A + (size_t)tm * 256 * KB;
  const char* Bb = (const char*)B + (size_t)tn * 256 * KB;

  // staging: LDS dest linear (uniform base, HW adds lane*16); source carries
  // the inverse swizzle: lane l covers (row rb+(l>>3), slot l&7), and LDS
  // slot m of row R must hold global col (m*16) ^ ((R&7)<<4).
  const int srccol = ((lane & 7) * 16) ^ ((lane >> 3) << 4);
  const int lrow = lane >> 3;
  // ds_read: row = lane&15 within 16-row fragment; col XORed with (row&7)<<4
  const int fragRow = lane & 15;
  const int swz = (lane & 7) << 4;
  const int colb0 = (lane >> 4) * 16;
  const int aOff = (wr * 128 + fragRow) * 128;           // row byte base (A)
  const int bOff = 32768 + (wc * 64 + fragRow) * 128;    // row byte base (B)

  f32x4 acc[8][4] = {};
  s16x8 a[4][2];     // current A mh: 4 mi x 2 ks
  s16x8 b[2][2][2];  // both B halves: [nh][ni2][ks]

#define STAGE_A(par, hs, kt)                                                  \
  _Pragma("unroll") for (int j = 0; j < 2; ++j) {                             \
    int c = w * 2 + j;                                                        \
    int rb = (c < 8) ? (hs)*64 + c * 8 : 128 + (hs)*64 + (c - 8) * 8;         \
    GL16(Ab + (size_t)(rb + lrow) * KB + (kt)*128 + srccol,                   \
         smem + (par)*65536 + rb * 128);                                      \
  }
#define STAGE_B(par, hs, kt)                                                  \
  _Pragma("unroll") for (int j = 0; j < 2; ++j) {                             \
    int c = w * 2 + j;                                                        \
    int rb = (c >> 2) * 64 + (hs)*32 + (c & 3) * 8;                           \
    GL16(Bb + (size_t)(rb + lrow) * KB + (kt)*128 + srccol,                   \
         smem + (par)*65536 + 32768 + rb * 128);                              \
  }
#define LDA(par, mh)                                                          \
  _Pragma("unroll") for (int mi2 = 0; mi2 < 4; ++mi2)                         \
  _Pragma("unroll") for (int ks = 0; ks < 2; ++ks)                            \
    a[mi2][ks] = *(const s16x8*)(smem + (par)*65536 + aOff + (mh)*8192 +      \
                                 mi2 * 2048 + ((colb0 + ks * 64) ^ swz));
#define LDB(par, nh)                                                          \
  _Pragma("unroll") for (int ni2 = 0; ni2 < 2; ++ni2)                         \
  _Pragma("unroll") for (int ks = 0; ks < 2; ++ks)                            \
    b[nh][ni2][ks] = *(const s16x8*)(smem + (par)*65536 + bOff + (nh)*4096 +  \
                                     ni2 * 2048 + ((colb0 + ks * 64) ^ swz));
#define VM6() asm volatile("s_waitcnt vmcnt(6)" ::: "memory")
#define BAR() asm volatile("s_barrier" ::: "memory")
#define BARL() asm volatile("s_barrier\n\ts_waitcnt lgkmcnt(0)" ::: "memory")
#define QM(mh, nh)                                                            \
  do {                                                                        \
    __builtin_amdgcn_s_setprio(1);                                            \
    _Pragma("unroll") for (int mi2 = 0; mi2 < 4; ++mi2)                       \
    _Pragma("unroll") for (int ni2 = 0; ni2 < 2; ++ni2)                       \
    _Pragma("unroll") for (int ks = 0; ks < 2; ++ks)                          \
      acc[(mh)*4 + mi2][(nh)*2 + ni2] =                                       \
          __builtin_amdgcn_mfma_f32_16x16x32_bf16(                            \
              a[mi2][ks], b[nh][ni2][ks], acc[(mh)*4 + mi2][(nh)*2 + ni2],    \
              0, 0, 0);                                                       \
    __builtin_amdgcn_s_setprio(0);                                            \
    BAR();                                                                    \
  } while (0)

  // prologue: t0 fully (par0), t1 first 3 halves (par1); vmcnt(6) -> t0 landed
  STAGE_A(0, 0, 0); STAGE_B(0, 0, 0); STAGE_B(0, 1, 0); STAGE_A(0, 1, 0);
  STAGE_A(1, 0, 1); STAGE_B(1, 0, 1); STAGE_B(1, 1, 1);
  VM6();
  BAR();

#pragma unroll 1
  for (int i = 0; i < NT / 2; ++i) {
    const int t2 = (2 * i + 2 < NT) ? 2 * i + 2 : NT - 1;  // clamped prefetch
    const int t3 = (2 * i + 3 < NT) ? 2 * i + 3 : NT - 1;
    // P1: consume e(A-h0,B-h0); stage odd tile's last half (Ao h1)
    LDA(0, 0); LDB(0, 0);
    STAGE_A(1, 1, 2 * i + 1);
    BARL(); QM(0, 0);
    // P2: consume e(B-h1); stage Ae h0 of t+2 (freed P1)
    LDB(0, 1);
    STAGE_A(0, 0, t2);
    BARL(); QM(0, 1);
    // P3: consume e(A-h1); stage Be h0 of t+2 (freed P1)
    LDA(0, 1);
    STAGE_B(0, 0, t2);
    BARL(); QM(1, 1);
    // P4: stage Be h1 of t+2 (freed P2); vmcnt(6) -> odd tile complete
    STAGE_B(0, 1, t2);
    VM6();
    BARL(); QM(1, 0);
    // P5: consume o(A-h0,B-h0); stage Ae h1 of t+2 (freed P3)
    LDA(1, 0); LDB(1, 0);
    STAGE_A(0, 1, t2);
    BARL(); QM(0, 0);
    // P6: stage Ao h0 of t+3 (freed P5)
    LDB(1, 1);
    STAGE_A(1, 0, t3);
    BARL(); QM(0, 1);
    // P7: stage Bo h0 of t+3 (freed P5)
    LDA(1, 1);
    STAGE_B(1, 0, t3);
    BARL(); QM(1, 1);
    // P8: stage Bo h1 of t+3 (freed P6); vmcnt(6) -> next even tile complete
    STAGE_B(1, 1, t3);
    VM6();
    BARL(); QM(1, 0);
  }

  // epilogue: write bf16 sim
  const int rowb = tm * 256 + wr * 128 + (lane >> 4) * 4;
  const int colb = tn * 256 + wc * 64 + (lane & 15);
#pragma unroll
  for (int mi = 0; mi < 8; ++mi)
#pragma unroll
    for (int ni = 0; ni < 4; ++ni)
#pragma unroll
      for (int j = 0; j < 4; ++j)
        C[(size_t)(rowb + mi * 16 + j) * NPAD + colb + ni * 16] =
            f2bf(acc[mi][ni][j]);
}

// ------------- argmax per pixel row + f64 rescore of near-ties --------------
__global__ __launch_bounds__(256) void k_argmax(const short* __restrict__ sim,
                                                const float* __restrict__ x,
                                                const float* __restrict__ pat,
                                                int* __restrict__ amax) {
  __shared__ int cand[4][32];
  __shared__ int ccnt[4];
  const int tid = threadIdx.x, w = tid >> 6, lane = tid & 63;
  const int pix = blockIdx.x * 4 + w;  // grid is exactly 6084/4
  const short* row = sim + (size_t)pix * NPAD;

  float best = -1e30f;
  int bidx = 0;
  for (int it = 0; it < 12; ++it) {
    int k0 = (it * 64 + lane) * 8;
    if (k0 < NPIX) {
      s16x8 v = *(const s16x8*)(row + k0);
#pragma unroll
      for (int j = 0; j < 8; ++j) {
        int k = k0 + j;
        float f = bf2f(v[j]);
        if (k < NPIX && (f > best || (f == best && k < bidx))) {
          best = f; bidx = k;
        }
      }
    }
  }
  for (int off = 32; off; off >>= 1) {
    float ov = __shfl_down(best, off);
    int oi = __shfl_down(bidx, off);
    if (ov > best || (ov == best && oi < bidx)) { best = ov; bidx = oi; }
  }
  float maxv = __shfl(best, 0);

  if (lane == 0) ccnt[w] = 0;
  __syncthreads();

  const float thr = maxv - 4.0f;  // covers bf16 matmul + storage error
  for (int it = 0; it < 12; ++it) {
    int k0 = (it * 64 + lane) * 8;
    if (k0 < NPIX) {
      s16x8 v = *(const s16x8*)(row + k0);
#pragma unroll
      for (int j = 0; j < 8; ++j) {
        int k = k0 + j;
        float f = bf2f(v[j]);
        if (k < NPIX && f >= thr) {
          int pos = atomicAdd(&ccnt[w], 1);
          if (pos < 32) cand[w][pos] = k;
        }
      }
    }
  }
  __syncthreads();

  int n = ccnt[w] < 32 ? ccnt[w] : 32;
  const int p = pix / 78, q = pix - (pix / 78) * 78;
  double bests = -1e300;
  int bestk = 0;
  for (int ci = 0; ci < n; ++ci) {
    int k = cand[w][ci];
    double s = 0.0;
    for (int cc = lane; cc < 256; cc += 64) {
      const float* xb = x + cc * 6400 + p * 80 + q;
      const float* pb = pat + (size_t)k * KDIM + cc * 9;
#pragma unroll
      for (int dy = 0; dy < 3; ++dy)
#pragma unroll
        for (int dx = 0; dx < 3; ++dx)
          s += (double)xb[dy * 80 + dx] * (double)pb[dy * 3 + dx];
    }
    for (int off = 32; off; off >>= 1) s += __shfl_down(s, off);
    if (lane == 0 && (s > bests || (s == bests && k < bestk))) {
      bests = s; bestk = k;
    }
  }
  if (lane == 0) amax[pix] = bestk;
}

// ------- scatter9: collision-free scatter into 9 shift planes ---------------
__global__ __launch_bounds__(256) void k_scat9(const float* __restrict__ pat,
                                               const int* __restrict__ amax,
                                               float* __restrict__ plane) {
  __shared__ float lp[KDIM];
  const int b = blockIdx.x;            // 6084 source pixels
  const int k = amax[b];
  const int p = b / 78, q = b - (b / 78) * 78;
  const float* src = pat + (size_t)k * KDIM;
#pragma unroll
  for (int j = 0; j < 9; ++j) lp[j * 256 + threadIdx.x] = src[j * 256 + threadIdx.x];
  __syncthreads();
  const int c = threadIdx.x;
#pragma unroll
  for (int r = 0; r < 9; ++r) {
    int dy = r / 3, dx = r - dy * 3;
    int pos = (p + dy) * 80 + (q + dx);   // always in [0,6400)
    plane[(size_t)r * 1638400 + pos * 256 + c] = lp[c * 9 + r];
  }
}

// ------- reduce: out[c][pix] = sum over valid planes / analytic count -------
__global__ __launch_bounds__(256) void k_reduce(const float* __restrict__ plane,
                                                float* __restrict__ out) {
  const int c = threadIdx.x;
  const int pix0 = blockIdx.x * 16;
  for (int i = 0; i < 16; ++i) {
    int pix = pix0 + i;
    int yy = pix / 80, xx = pix - (pix / 80) * 80;
    float s = 0.f;
    int cnt = 0;
#pragma unroll
    for (int r = 0; r < 9; ++r) {
      int dy = r / 3, dx = r - dy * 3;
      int p = yy - dy, q = xx - dx;
      if (p >= 0 && p < 78 && q >= 0 && q < 78) {
        s += plane[(size_t)r * 1638400 + pix * 256 + c];
        ++cnt;
      }
    }
    out[c * 6400 + pix] = s / (float)cnt;
  }
}

extern "C" void kernel_launch(void* const* d_in, const int* in_sizes, int n_in,
                              void* d_out, int out_size, void* d_ws,
                              size_t ws_size, hipStream_t stream) {
  const float* x = (const float*)d_in[0];    // (1,256,80,80) f32
  const float* pat = (const float*)d_in[1];  // (6084,256,3,3) f32
  float* out = (float*)d_out;                // (1,256,80,80) f32
  char* ws = (char*)d_ws;

  short* patB = (short*)ws;                          // 28,311,552 B
  short* xcol = (short*)(ws + 28311552);             // 28,311,552 B
  short* sim  = (short*)(ws + 2 * 28311552);         // 75,497,472 B
  float* plane = (float*)sim;                        // 58,982,400 B (overlays dead sim)
  int*   amax = (int*)(ws + 2 * 28311552 + 75497472);// 24,336 B

  k_prep_pat<<<6912, 256, 0, stream>>>(pat, patB);
  k_prep_xcol<<<6912, 256, 0, stream>>>(x, xcol);
  k_gemm<<<dim3(24, 24), 512, 0, stream>>>(xcol, patB, sim);
  k_argmax<<<1521, 256, 0, stream>>>(sim, x, pat, amax);
  k_scat9<<<6084, 256, 0, stream>>>(pat, amax, plane);
  k_reduce<<<400, 256, 0, stream>>>(plane, out);
}